// Round 7
// baseline (444.862 us; speedup 1.0000x reference)
//
#include <hip/hip_runtime.h>

typedef _Float16 half8 __attribute__((ext_vector_type(8)));
typedef float floatx4 __attribute__((ext_vector_type(4)));

__device__ __forceinline__ float fast_sigmoid(float x) {
    return __builtin_amdgcn_rcpf(1.0f + __expf(-x));
}
__device__ __forceinline__ float fast_tanh(float x) {
    return 1.0f - 2.0f * __builtin_amdgcn_rcpf(__expf(2.0f * x) + 1.0f);
}

// Barrier that does NOT drain vmem (verified r2->r3): only LDS ops published.
// 0xC07F = vmcnt(63) expcnt(7) lgkmcnt(0).
template<bool MULTI_WAVE>
__device__ __forceinline__ void lds_publish_barrier() {
    asm volatile("" ::: "memory");
    __builtin_amdgcn_s_waitcnt(0xC07F);
    if constexpr (MULTI_WAVE) __builtin_amdgcn_s_barrier();
    asm volatile("" ::: "memory");
}

// ---------- pack Wk weights + bias into per-(dir,wave,lane) MFMA B-fragments.
// Record per thread: [g=0..3][kt=0..XT) half8 contiguous; bias float4.
// Kills the ~96 strided scalar gathers per gemm thread (one-time, tiny).
template<int F_REAL, int XT, int U>
__device__ __forceinline__ void pack_one(int dir, int wave, int lane,
    const float* Wk_f, const float* b_f, const float* Wk_b, const float* b_b,
    half8* wf, float4* bf4)
{
    constexpr int N  = 4 * U;
    constexpr int NW = U / 16;
    const int quad = lane >> 4, l16 = lane & 15;
    const float* Wk = dir ? Wk_b : Wk_f;
    const float* bs = dir ? b_b  : b_f;
    const int ucol = wave * 16 + l16;
    const long base = ((long)(dir * NW + wave) * 64 + lane) * (4 * XT);
    #pragma unroll
    for (int g = 0; g < 4; g++) {
        const int n = g * U + ucol;
        #pragma unroll
        for (int kt = 0; kt < XT; kt++) {
            half8 h;
            #pragma unroll
            for (int j = 0; j < 8; j++) {
                const int k = kt * 32 + quad * 8 + j;
                h[j] = (k < F_REAL) ? (_Float16)Wk[k * N + n] : (_Float16)0;
            }
            wf[base + g * XT + kt] = h;
        }
    }
    float4 b;
    b.x = bs[0 * U + ucol]; b.y = bs[1 * U + ucol];
    b.z = bs[2 * U + ucol]; b.w = bs[3 * U + ucol];
    bf4[(dir * NW + wave) * 64 + lane] = b;
}

__global__ __launch_bounds__(256)
void pack_wk(const float* w1f_k, const float* w1f_b, const float* w1b_k, const float* w1b_b,
             const float* w2f_k, const float* w2f_b, const float* w2b_k, const float* w2b_b,
             const float* w3f_k, const float* w3f_b, const float* w3b_k, const float* w3b_b,
             half8* wf, float4* bf4)
{
    const int t = blockIdx.x * 256 + threadIdx.x;
    if (t < 512) {               // L1: 2 dir x 4 wave x 64 lane
        pack_one<78, 3, 64>(t >> 8, (t >> 6) & 3, t & 63,
                            w1f_k, w1f_b, w1b_k, w1b_b, wf, bf4);
    } else if (t < 768) {        // L2: 2 x 2 x 64
        const int t2 = t - 512;
        pack_one<128, 4, 32>(t2 >> 7, (t2 >> 6) & 1, t2 & 63,
                             w2f_k, w2f_b, w2b_k, w2b_b, wf + 6144, bf4 + 512);
    } else if (t < 896) {        // L3: 2 x 1 x 64
        const int t3 = t - 768;
        pack_one<64, 2, 16>(t3 >> 6, 0, t3 & 63,
                            w3f_k, w3f_b, w3b_k, w3b_b, wf + 10240, bf4 + 768);
    }
}

// ---------- xz GEMM: z = in @ Wk + b, gate-sliced cols, stored f16 in the
// exact C-fragment record the recurrence lane consumes (32 B contiguous).
// M-tile = 16 rows = 8 chains x 2 timesteps. No LDS. Packed weight frags,
// double-buffered A-prefetch across the t-loop.
// Record: xz[((dir*128+bg)*T + t)*NW + w][q2][l16][g*4+r] f16.
template<int F_REAL, int XT, int U, bool IN_F32, int TPC>
__global__ __launch_bounds__(64 * (U / 16))
void xz_gemm(const void* __restrict__ in_,    // rows of F_REAL elems, row = b*T + t_x
             const half8* __restrict__ wf, const float4* __restrict__ bf4,
             _Float16* __restrict__ xz)
{
    constexpr int T  = 128;
    constexpr int NW = U / 16;

    const int tid  = threadIdx.x;
    const int wave = tid >> 6;
    const int lane = tid & 63;
    const int quad = lane >> 4;
    const int l16  = lane & 15;

    const int bg  = blockIdx.x & 127;
    const int dir = (blockIdx.x >> 7) & 1;
    const int tc  = blockIdx.x >> 8;

    // packed weight fragments: contiguous vector loads
    const long wbase = ((long)(dir * NW + wave) * 64 + lane) * (4 * XT);
    half8 bf[4][XT];
    #pragma unroll
    for (int g = 0; g < 4; g++)
        #pragma unroll
        for (int kt = 0; kt < XT; kt++)
            bf[g][kt] = wf[wbase + g * XT + kt];
    const float4 bias4 = bf4[(dir * NW + wave) * 64 + lane];
    const float bias[4] = {bias4.x, bias4.y, bias4.z, bias4.w};

    // A row m = l16 -> chain (l16&7), t = 2tp + (l16>>3)
    const int brow   = bg * 8 + (l16 & 7);
    const int tsel_a = l16 >> 3;
    // C rows quad*4+r -> chain (quad&1)*4+r, t = 2tp + (quad>>1)
    const int q2     = quad & 1;
    const int tsel_c = quad >> 1;

    auto load_a = [&](int tp, half8* a) {
        const int t_a = 2 * tp + tsel_a;
        const int t_x = dir ? (T - 1 - t_a) : t_a;
        #pragma unroll
        for (int kt = 0; kt < XT; kt++) {
            const int kb = kt * 32 + quad * 8;
            if constexpr (IN_F32) {
                const float* p = (const float*)in_ + ((long)brow * T + t_x) * F_REAL + kb;
                half8 h;
                #pragma unroll
                for (int j = 0; j < 8; j += 2) {
                    float v0, v1;
                    if ((kt + 1) * 32 <= F_REAL) {          // whole tile in-bounds (compile-time)
                        const float2 v = *(const float2*)(p + j);
                        v0 = v.x; v1 = v.y;
                    } else {
                        const int k = kb + j;
                        v0 = 0.0f; v1 = 0.0f;
                        if (k + 2 <= F_REAL) { const float2 v = *(const float2*)(p + j); v0 = v.x; v1 = v.y; }
                        else if (k < F_REAL) { v0 = p[j]; }
                    }
                    h[j] = (_Float16)v0; h[j + 1] = (_Float16)v1;
                }
                a[kt] = h;
            } else {
                const _Float16* p = (const _Float16*)in_ + ((long)brow * T + t_x) * F_REAL;
                a[kt] = *(const half8*)(p + kb);   // F_REAL % 32 == 0 for f16 inputs
            }
        }
    };

    half8 areg[2][XT];
    load_a(tc * TPC, areg[0]);

    #pragma unroll
    for (int i = 0; i < TPC; i++) {
        const int tp = tc * TPC + i;
        // prefetch next t-pair's A before consuming current (stays in flight
        // across the MFMA + store issue below)
        if (i + 1 < TPC) load_a(tp + 1, areg[(i + 1) & 1]);

        floatx4 acc[4];
        #pragma unroll
        for (int g = 0; g < 4; g++) {
            floatx4 v = {bias[g], bias[g], bias[g], bias[g]};
            acc[g] = v;
        }
        #pragma unroll
        for (int kt = 0; kt < XT; kt++) {
            const half8 a = areg[i & 1][kt];
            #pragma unroll
            for (int g = 0; g < 4; g++)
                acc[g] = __builtin_amdgcn_mfma_f32_16x16x32_f16(a, bf[g][kt], acc[g], 0, 0, 0);
        }
        half8 lo, hi;
        #pragma unroll
        for (int r = 0; r < 4; r++) {
            lo[r]     = (_Float16)acc[0][r];
            lo[4 + r] = (_Float16)acc[1][r];
            hi[r]     = (_Float16)acc[2][r];
            hi[4 + r] = (_Float16)acc[3][r];
        }
        const int t_c = 2 * tp + tsel_c;
        _Float16* op = xz + (((((long)(dir * 128 + bg) * T + t_c) * NW + wave) * 2 + q2) * 256 + l16 * 16);
        *(half8*)op       = lo;
        *(half8*)(op + 8) = hi;
    }
}

// ---------- recurrence: only h@Wr + gates on the serial path.
// A rows 8..15 duplicate rows 0..7 (ds_read H[l16&7], same-address broadcast)
// so quads 2,3 natively hold correct full z for chains 0..7 -> NO shuffles.
template<int U, int HT, bool SEQ_OUT>
__global__ __launch_bounds__(64 * (U / 16))
void lstm_rec(const _Float16* __restrict__ xz,
              const float* __restrict__ Wr_f, const float* __restrict__ Wr_b,
              _Float16* __restrict__ hseq, float* __restrict__ hlast)
{
    constexpr int T    = 128;
    constexpr int N    = 4 * U;
    constexpr int NW   = U / 16;
    constexpr int HROW = HT * 32 + 8;        // f16/row, 16B-aligned stride
    constexpr int THREADS = NW * 64;

    const int tid  = threadIdx.x;
    const int wave = tid >> 6;
    const int lane = tid & 63;
    const int quad = lane >> 4;
    const int l16  = lane & 15;

    const int dir   = blockIdx.x >> 7;
    const int bg    = blockIdx.x & 127;
    const int bbase = bg * 8;

    const float* Wr = dir ? Wr_b : Wr_f;

    __shared__ __align__(16) _Float16 H[2][8][HROW];
    for (int i = tid; i < 2 * 8 * HROW; i += THREADS)
        (&H[0][0][0])[i] = (_Float16)0;      // h0=0; pad and u>=U stay 0

    const int ucol = wave * 16 + l16;
    half8 bf[4][HT];
    #pragma unroll
    for (int g = 0; g < 4; g++) {
        const int n = g * U + ucol;
        #pragma unroll
        for (int ht = 0; ht < HT; ht++) {
            half8 h;
            #pragma unroll
            for (int j = 0; j < 8; j++) {
                const int k = ht * 32 + quad * 8 + j;
                h[j] = (k < U) ? (_Float16)Wr[k * N + n] : (_Float16)0;
            }
            bf[g][ht] = h;
        }
    }

    // quad -> 2 chains: q0:{0,1} q1:{4,5} q2:{2,3} q3:{6,7}
    const int rowbase = (quad & 1) * 4 + (quad >> 1) * 2;
    const bool hi_rows = (quad & 2) != 0;
    float c_reg[2] = {0.0f, 0.0f};

    const long rec_base = ((long)(dir * 128 + bg) * T) * (NW * 512)
                        + ((long)wave * 2 + (quad & 1)) * 256 + l16 * 16;

    auto load_xz = [&](int t, half8* z) {
        const int tc = t < T ? t : T - 1;
        const _Float16* p = xz + rec_base + (long)tc * (NW * 512);
        z[0] = *(const half8*)p;
        z[1] = *(const half8*)(p + 8);
    };

    const int tp0 = dir ? (T - 1) : 0;
    const long hs_stride = (long)T * (2 * U);
    _Float16* hs_ptr = SEQ_OUT
        ? hseq + ((long)(bbase + rowbase) * T + tp0) * (2 * U) + dir * U + ucol
        : nullptr;
    const long hs_delta = dir ? -(long)(2 * U) : (long)(2 * U);

    auto step = [&](int t, half8* z) {
        floatx4 acc[4];
        #pragma unroll
        for (int g = 0; g < 4; g++) {
            #pragma unroll
            for (int r = 0; r < 4; r++)
                acc[g][r] = (float)z[g >> 1][(g & 1) * 4 + r];
        }
        load_xz(t + 2, z);                   // stays in flight across barrier
        lds_publish_barrier<(NW > 1)>();
        const _Float16* hb = &H[t & 1][l16 & 7][0];   // rows 8..15 = dup of 0..7
        #pragma unroll
        for (int ht = 0; ht < HT; ht++) {
            const half8 ha = *(const half8*)(hb + ht * 32 + quad * 8);
            #pragma unroll
            for (int g = 0; g < 4; g++)
                acc[g] = __builtin_amdgcn_mfma_f32_16x16x32_f16(ha, bf[g][ht], acc[g], 0, 0, 0);
        }
        float hq[2];
        #pragma unroll
        for (int s = 0; s < 2; s++) {
            const int r = hi_rows ? (2 + s) : s;
            const float ig = fast_sigmoid(acc[0][r]);
            const float fg = fast_sigmoid(acc[1][r]);
            const float gg = fast_tanh(acc[2][r]);
            const float og = fast_sigmoid(acc[3][r]);
            const float c  = fg * c_reg[s] + ig * gg;
            c_reg[s] = c;
            hq[s] = og * fast_tanh(c);
        }
        #pragma unroll
        for (int s = 0; s < 2; s++)
            H[(t + 1) & 1][rowbase + s][ucol] = (_Float16)hq[s];
        if constexpr (SEQ_OUT) {
            #pragma unroll
            for (int s = 0; s < 2; s++)
                hs_ptr[s * hs_stride] = (_Float16)hq[s];
            hs_ptr += hs_delta;
        } else {
            if (t == T - 1) {
                #pragma unroll
                for (int s = 0; s < 2; s++)
                    hlast[(bbase + rowbase + s) * (2 * U) + dir * U + ucol] = hq[s];
            }
        }
    };

    half8 za[2], zb[2];
    load_xz(0, za);
    load_xz(1, zb);
    __syncthreads();                          // H zero-init visible (once)

    for (int tt = 0; tt < T; tt += 2) {
        step(tt,     za);
        step(tt + 1, zb);
    }
}

__global__ __launch_bounds__(256)
void dense_head(const float* __restrict__ h3,
                const float* __restrict__ w1, const float* __restrict__ b1,
                const float* __restrict__ w2, const float* __restrict__ b2,
                float* __restrict__ out)
{
    const int r = blockIdx.x * 256 + threadIdx.x;
    if (r >= 1024) return;
    float h[32];
    #pragma unroll
    for (int k = 0; k < 32; k++) h[k] = h3[r * 32 + k];
    float d1[8];
    #pragma unroll
    for (int j = 0; j < 8; j++) {
        float a = b1[j];
        #pragma unroll
        for (int k = 0; k < 32; k++) a += h[k] * w1[k * 8 + j];
        d1[j] = fmaxf(a, 0.0f);
    }
    #pragma unroll
    for (int c = 0; c < 3; c++) {
        float s = b2[c];
        #pragma unroll
        for (int j = 0; j < 8; j++) s += d1[j] * w2[j * 3 + c];
        out[r * 3 + c] = 1.0f / (1.0f + __expf(-s));
    }
}

extern "C" void kernel_launch(void* const* d_in, const int* in_sizes, int n_in,
                              void* d_out, int out_size, void* d_ws, size_t ws_size,
                              hipStream_t stream) {
    const float* x     = (const float*)d_in[0];
    const float* w1f_k = (const float*)d_in[1];
    const float* w1f_r = (const float*)d_in[2];
    const float* w1f_b = (const float*)d_in[3];
    const float* w1b_k = (const float*)d_in[4];
    const float* w1b_r = (const float*)d_in[5];
    const float* w1b_b = (const float*)d_in[6];
    const float* w2f_k = (const float*)d_in[7];
    const float* w2f_r = (const float*)d_in[8];
    const float* w2f_b = (const float*)d_in[9];
    const float* w2b_k = (const float*)d_in[10];
    const float* w2b_r = (const float*)d_in[11];
    const float* w2b_b = (const float*)d_in[12];
    const float* w3f_k = (const float*)d_in[13];
    const float* w3f_r = (const float*)d_in[14];
    const float* w3f_b = (const float*)d_in[15];
    const float* w3b_k = (const float*)d_in[16];
    const float* w3b_r = (const float*)d_in[17];
    const float* w3b_b = (const float*)d_in[18];
    const float* d3_w  = (const float*)d_in[19];
    const float* d3_b  = (const float*)d_in[20];
    const float* cls_w = (const float*)d_in[21];
    const float* cls_b = (const float*)d_in[22];

    char* ws = (char*)d_ws;
    // Arena A (reused 3x): xz1 134.2MB -> xz2 67.1MB -> xz3 33.6MB
    _Float16* xz = (_Float16*)ws;
    _Float16* h1 = (_Float16*)(ws + 134217728);                  // 32MB
    _Float16* h2 = (_Float16*)(ws + 134217728 + 33554432);       // 16.8MB
    float*    h3 = (float*)   (ws + 134217728 + 33554432 + 16777216);
    half8*    wf = (half8*)   (ws + 184680448);                  // 176KB packed frags
    float4*  bf4 = (float4*)  (ws + 184680448 + 180224);         // 14KB biases

    pack_wk<<<dim3(4), dim3(256), 0, stream>>>(
        w1f_k, w1f_b, w1b_k, w1b_b, w2f_k, w2f_b, w2b_k, w2b_b,
        w3f_k, w3f_b, w3b_k, w3b_b, wf, bf4);

    // L1: F=78 (3 k-tiles, fp32 in), U=64; TPC=4 -> 4096 blocks
    xz_gemm<78, 3, 64, true, 4><<<dim3(4096), dim3(256), 0, stream>>>(
        x, wf, bf4, xz);
    lstm_rec<64, 2, true><<<dim3(256), dim3(256), 0, stream>>>(
        xz, w1f_r, w1b_r, h1, nullptr);

    // L2: F=128, U=32
    xz_gemm<128, 4, 32, false, 4><<<dim3(4096), dim3(128), 0, stream>>>(
        h1, wf + 6144, bf4 + 512, xz);
    lstm_rec<32, 1, true><<<dim3(256), dim3(128), 0, stream>>>(
        xz, w2f_r, w2b_r, h2, nullptr);

    // L3: F=64, U=16
    xz_gemm<64, 2, 16, false, 4><<<dim3(4096), dim3(64), 0, stream>>>(
        h2, wf + 10240, bf4 + 768, xz);
    lstm_rec<16, 1, false><<<dim3(256), dim3(64), 0, stream>>>(
        xz, w3f_r, w3b_r, nullptr, h3);

    dense_head<<<dim3(4), dim3(256), 0, stream>>>(h3, d3_w, d3_b, cls_w, cls_b, (float*)d_out);
}

// Round 8
// 397.688 us; speedup vs baseline: 1.1186x; 1.1186x over previous
//
#include <hip/hip_runtime.h>

typedef _Float16 half8 __attribute__((ext_vector_type(8)));
typedef float floatx4 __attribute__((ext_vector_type(4)));

__device__ __forceinline__ float fast_sigmoid(float x) {
    return __builtin_amdgcn_rcpf(1.0f + __expf(-x));
}
__device__ __forceinline__ float fast_tanh(float x) {
    return 1.0f - 2.0f * __builtin_amdgcn_rcpf(__expf(2.0f * x) + 1.0f);
}

// Barrier that does NOT drain vmem (verified r2->r3): only LDS ops published.
// 0xC07F = vmcnt(63) expcnt(7) lgkmcnt(0).
template<bool MULTI_WAVE>
__device__ __forceinline__ void lds_publish_barrier() {
    asm volatile("" ::: "memory");
    __builtin_amdgcn_s_waitcnt(0xC07F);
    if constexpr (MULTI_WAVE) __builtin_amdgcn_s_barrier();
    asm volatile("" ::: "memory");
}

// ---------- pack Wk weights + bias into per-(dir,wave,lane) MFMA B-fragments.
template<int F_REAL, int XT, int U>
__device__ __forceinline__ void pack_one(int dir, int wave, int lane,
    const float* Wk_f, const float* b_f, const float* Wk_b, const float* b_b,
    half8* wf, float4* bf4)
{
    constexpr int N  = 4 * U;
    constexpr int NW = U / 16;
    const int quad = lane >> 4, l16 = lane & 15;
    const float* Wk = dir ? Wk_b : Wk_f;
    const float* bs = dir ? b_b  : b_f;
    const int ucol = wave * 16 + l16;
    const long base = ((long)(dir * NW + wave) * 64 + lane) * (4 * XT);
    #pragma unroll
    for (int g = 0; g < 4; g++) {
        const int n = g * U + ucol;
        #pragma unroll
        for (int kt = 0; kt < XT; kt++) {
            half8 h;
            #pragma unroll
            for (int j = 0; j < 8; j++) {
                const int k = kt * 32 + quad * 8 + j;
                h[j] = (k < F_REAL) ? (_Float16)Wk[k * N + n] : (_Float16)0;
            }
            wf[base + g * XT + kt] = h;
        }
    }
    float4 b;
    b.x = bs[0 * U + ucol]; b.y = bs[1 * U + ucol];
    b.z = bs[2 * U + ucol]; b.w = bs[3 * U + ucol];
    bf4[(dir * NW + wave) * 64 + lane] = b;
}

__global__ __launch_bounds__(256)
void pack_wk(const float* w1f_k, const float* w1f_b, const float* w1b_k, const float* w1b_b,
             const float* w2f_k, const float* w2f_b, const float* w2b_k, const float* w2b_b,
             const float* w3f_k, const float* w3f_b, const float* w3b_k, const float* w3b_b,
             half8* wf, float4* bf4)
{
    const int t = blockIdx.x * 256 + threadIdx.x;
    if (t < 512) {               // L1: 2 dir x 4 wave x 64 lane
        pack_one<78, 3, 64>(t >> 8, (t >> 6) & 3, t & 63,
                            w1f_k, w1f_b, w1b_k, w1b_b, wf, bf4);
    } else if (t < 768) {        // L2: 2 x 2 x 64
        const int t2 = t - 512;
        pack_one<128, 4, 32>(t2 >> 7, (t2 >> 6) & 1, t2 & 63,
                             w2f_k, w2f_b, w2b_k, w2b_b, wf + 6144, bf4 + 512);
    } else if (t < 896) {        // L3: 2 x 1 x 64
        const int t3 = t - 768;
        pack_one<64, 2, 16>(t3 >> 6, 0, t3 & 63,
                            w3f_k, w3f_b, w3b_k, w3b_b, wf + 10240, bf4 + 768);
    }
}

// ---------- xz GEMM: z = in @ Wk + b, gate-sliced cols, stored f16 in the
// exact C-fragment record the recurrence lane consumes.
// STAGE path (r8): X tile staged once per block into LDS (coalesced,
// f16-converted, double-buffered) -> all NW waves ds_read A-frags. Fixes the
// r7 L1/TA request bound (4x wave-redundant 16-line scattered loads).
// Record: xz[((dir*128+bg)*T + t)*NW + w][q2][l16][g*4+r] f16.
template<int F_REAL, int FP, int XT, int U, bool IN_F32, int TPC, bool STAGE>
__global__ __launch_bounds__(64 * (U / 16))
void xz_gemm(const void* __restrict__ in_,    // rows of F_REAL elems, row = b*T + t_x
             const half8* __restrict__ wf, const float4* __restrict__ bf4,
             _Float16* __restrict__ xz)
{
    constexpr int T    = 128;
    constexpr int NW   = U / 16;
    constexpr int THREADS = NW * 64;
    constexpr int CPR  = FP / 8;               // 8-f16 chunks per row
    constexpr int CH   = 16 * CPR;             // chunks per tile
    constexpr int SPT  = (CH + THREADS - 1) / THREADS;
    constexpr int ROWP = FP + 8;               // +16B pad: bank period 8 -> 2-way (free)

    const int tid  = threadIdx.x;
    const int wave = tid >> 6;
    const int lane = tid & 63;
    const int quad = lane >> 4;
    const int l16  = lane & 15;

    const int bg  = blockIdx.x & 127;
    const int dir = (blockIdx.x >> 7) & 1;
    const int tc  = blockIdx.x >> 8;

    __shared__ __align__(16) _Float16 XS[2][16][ROWP];

    // packed weight fragments: contiguous vector loads
    const long wbase = ((long)(dir * NW + wave) * 64 + lane) * (4 * XT);
    half8 bf[4][XT];
    #pragma unroll
    for (int g = 0; g < 4; g++)
        #pragma unroll
        for (int kt = 0; kt < XT; kt++)
            bf[g][kt] = wf[wbase + g * XT + kt];
    const float4 bias4 = bf4[(dir * NW + wave) * 64 + lane];
    const float bias[4] = {bias4.x, bias4.y, bias4.z, bias4.w};

    // A row m -> chain (m&7), t = 2tp + (m>>3)
    const int brow   = bg * 8 + (l16 & 7);
    const int tsel_a = l16 >> 3;
    // C rows quad*4+r -> chain (quad&1)*4+r, t = 2tp + (quad>>1)
    const int q2     = quad & 1;
    const int tsel_c = quad >> 1;

    auto compute_store = [&](int tp, const half8* a) {
        floatx4 acc[4];
        #pragma unroll
        for (int g = 0; g < 4; g++) {
            floatx4 v = {bias[g], bias[g], bias[g], bias[g]};
            acc[g] = v;
        }
        #pragma unroll
        for (int kt = 0; kt < XT; kt++) {
            #pragma unroll
            for (int g = 0; g < 4; g++)
                acc[g] = __builtin_amdgcn_mfma_f32_16x16x32_f16(a[kt], bf[g][kt], acc[g], 0, 0, 0);
        }
        half8 lo, hi;
        #pragma unroll
        for (int r = 0; r < 4; r++) {
            lo[r]     = (_Float16)acc[0][r];
            lo[4 + r] = (_Float16)acc[1][r];
            hi[r]     = (_Float16)acc[2][r];
            hi[4 + r] = (_Float16)acc[3][r];
        }
        const int t_c = 2 * tp + tsel_c;
        _Float16* op = xz + (((((long)(dir * 128 + bg) * T + t_c) * NW + wave) * 2 + q2) * 256 + l16 * 16);
        *(half8*)op       = lo;
        *(half8*)(op + 8) = hi;
    };

    if constexpr (STAGE) {
        // cooperative tile load: chunk c -> row c/CPR, col 8*(c%CPR)
        auto load_tile = [&](int tp, half8* sreg) {
            #pragma unroll
            for (int s = 0; s < SPT; s++) {
                const int c = tid + s * THREADS;
                if (c < CH) {
                    const int row = c / CPR, col = (c - row * CPR) * 8;
                    const int t_a = 2 * tp + (row >> 3);
                    const int t_x = dir ? (T - 1 - t_a) : t_a;
                    const long ro = ((long)(bg * 8 + (row & 7)) * T + t_x) * F_REAL;
                    half8 h;
                    if constexpr (IN_F32) {
                        const float* p = (const float*)in_ + ro + col;
                        #pragma unroll
                        for (int j = 0; j < 8; j += 2) {
                            float v0 = 0.0f, v1 = 0.0f;
                            if (col + j < F_REAL) {   // F_REAL even, col+j even -> full pair
                                const float2 v = *(const float2*)(p + j);
                                v0 = v.x; v1 = v.y;
                            }
                            h[j] = (_Float16)v0; h[j + 1] = (_Float16)v1;
                        }
                    } else {
                        h = *(const half8*)((const _Float16*)in_ + ro + col);
                    }
                    sreg[s] = h;
                }
            }
        };
        auto stage_write = [&](int buf, const half8* sreg) {
            #pragma unroll
            for (int s = 0; s < SPT; s++) {
                const int c = tid + s * THREADS;
                if (c < CH) {
                    const int row = c / CPR, col = (c - row * CPR) * 8;
                    *(half8*)&XS[buf][row][col] = sreg[s];
                }
            }
        };

        half8 sreg[2][SPT];
        load_tile(tc * TPC, sreg[0]);
        #pragma unroll
        for (int i = 0; i < TPC; i++) {
            const int tp = tc * TPC + i;
            stage_write(i & 1, sreg[i & 1]);
            if (i + 1 < TPC) load_tile(tp + 1, sreg[(i + 1) & 1]);  // in flight
            lds_publish_barrier<true>();
            half8 a[XT];
            const _Float16* xb = &XS[i & 1][l16][0];
            #pragma unroll
            for (int kt = 0; kt < XT; kt++)
                a[kt] = *(const half8*)(xb + kt * 32 + quad * 8);
            compute_store(tp, a);
        }
    } else {
        // direct path (L3: single wave, no cross-wave duplication)
        auto load_a = [&](int tp, half8* a) {
            const int t_a = 2 * tp + tsel_a;
            const int t_x = dir ? (T - 1 - t_a) : t_a;
            const _Float16* p = (const _Float16*)in_ + ((long)brow * T + t_x) * F_REAL;
            #pragma unroll
            for (int kt = 0; kt < XT; kt++)
                a[kt] = *(const half8*)(p + kt * 32 + quad * 8);
        };
        half8 areg[2][XT];
        load_a(tc * TPC, areg[0]);
        #pragma unroll
        for (int i = 0; i < TPC; i++) {
            const int tp = tc * TPC + i;
            if (i + 1 < TPC) load_a(tp + 1, areg[(i + 1) & 1]);
            compute_store(tp, areg[i & 1]);
        }
    }
}

// ---------- recurrence: only h@Wr + gates on the serial path.
// A rows 8..15 duplicate rows 0..7 (ds_read H[l16&7], same-address broadcast)
// so quads 2,3 natively hold correct full z for chains 0..7 -> NO shuffles.
template<int U, int HT, bool SEQ_OUT>
__global__ __launch_bounds__(64 * (U / 16))
void lstm_rec(const _Float16* __restrict__ xz,
              const float* __restrict__ Wr_f, const float* __restrict__ Wr_b,
              _Float16* __restrict__ hseq, float* __restrict__ hlast)
{
    constexpr int T    = 128;
    constexpr int N    = 4 * U;
    constexpr int NW   = U / 16;
    constexpr int HROW = HT * 32 + 8;        // f16/row, 16B-aligned stride
    constexpr int THREADS = NW * 64;

    const int tid  = threadIdx.x;
    const int wave = tid >> 6;
    const int lane = tid & 63;
    const int quad = lane >> 4;
    const int l16  = lane & 15;

    const int dir   = blockIdx.x >> 7;
    const int bg    = blockIdx.x & 127;
    const int bbase = bg * 8;

    const float* Wr = dir ? Wr_b : Wr_f;

    __shared__ __align__(16) _Float16 H[2][8][HROW];
    for (int i = tid; i < 2 * 8 * HROW; i += THREADS)
        (&H[0][0][0])[i] = (_Float16)0;      // h0=0; pad and u>=U stay 0

    const int ucol = wave * 16 + l16;
    half8 bf[4][HT];
    #pragma unroll
    for (int g = 0; g < 4; g++) {
        const int n = g * U + ucol;
        #pragma unroll
        for (int ht = 0; ht < HT; ht++) {
            half8 h;
            #pragma unroll
            for (int j = 0; j < 8; j++) {
                const int k = ht * 32 + quad * 8 + j;
                h[j] = (k < U) ? (_Float16)Wr[k * N + n] : (_Float16)0;
            }
            bf[g][ht] = h;
        }
    }

    // quad -> 2 chains: q0:{0,1} q1:{4,5} q2:{2,3} q3:{6,7}
    const int rowbase = (quad & 1) * 4 + (quad >> 1) * 2;
    const bool hi_rows = (quad & 2) != 0;
    float c_reg[2] = {0.0f, 0.0f};

    const long rec_base = ((long)(dir * 128 + bg) * T) * (NW * 512)
                        + ((long)wave * 2 + (quad & 1)) * 256 + l16 * 16;

    auto load_xz = [&](int t, half8* z) {
        const int tc = t < T ? t : T - 1;
        const _Float16* p = xz + rec_base + (long)tc * (NW * 512);
        z[0] = *(const half8*)p;
        z[1] = *(const half8*)(p + 8);
    };

    const int tp0 = dir ? (T - 1) : 0;
    const long hs_stride = (long)T * (2 * U);
    _Float16* hs_ptr = SEQ_OUT
        ? hseq + ((long)(bbase + rowbase) * T + tp0) * (2 * U) + dir * U + ucol
        : nullptr;
    const long hs_delta = dir ? -(long)(2 * U) : (long)(2 * U);

    auto step = [&](int t, half8* z) {
        floatx4 acc[4];
        #pragma unroll
        for (int g = 0; g < 4; g++) {
            #pragma unroll
            for (int r = 0; r < 4; r++)
                acc[g][r] = (float)z[g >> 1][(g & 1) * 4 + r];
        }
        load_xz(t + 2, z);                   // stays in flight across barrier
        lds_publish_barrier<(NW > 1)>();
        const _Float16* hb = &H[t & 1][l16 & 7][0];   // rows 8..15 = dup of 0..7
        #pragma unroll
        for (int ht = 0; ht < HT; ht++) {
            const half8 ha = *(const half8*)(hb + ht * 32 + quad * 8);
            #pragma unroll
            for (int g = 0; g < 4; g++)
                acc[g] = __builtin_amdgcn_mfma_f32_16x16x32_f16(ha, bf[g][ht], acc[g], 0, 0, 0);
        }
        float hq[2];
        #pragma unroll
        for (int s = 0; s < 2; s++) {
            const int r = hi_rows ? (2 + s) : s;
            const float ig = fast_sigmoid(acc[0][r]);
            const float fg = fast_sigmoid(acc[1][r]);
            const float gg = fast_tanh(acc[2][r]);
            const float og = fast_sigmoid(acc[3][r]);
            const float c  = fg * c_reg[s] + ig * gg;
            c_reg[s] = c;
            hq[s] = og * fast_tanh(c);
        }
        #pragma unroll
        for (int s = 0; s < 2; s++)
            H[(t + 1) & 1][rowbase + s][ucol] = (_Float16)hq[s];
        if constexpr (SEQ_OUT) {
            #pragma unroll
            for (int s = 0; s < 2; s++)
                hs_ptr[s * hs_stride] = (_Float16)hq[s];
            hs_ptr += hs_delta;
        } else {
            if (t == T - 1) {
                #pragma unroll
                for (int s = 0; s < 2; s++)
                    hlast[(bbase + rowbase + s) * (2 * U) + dir * U + ucol] = hq[s];
            }
        }
    };

    half8 za[2], zb[2];
    load_xz(0, za);
    load_xz(1, zb);
    __syncthreads();                          // H zero-init visible (once)

    for (int tt = 0; tt < T; tt += 2) {
        step(tt,     za);
        step(tt + 1, zb);
    }
}

__global__ __launch_bounds__(256)
void dense_head(const float* __restrict__ h3,
                const float* __restrict__ w1, const float* __restrict__ b1,
                const float* __restrict__ w2, const float* __restrict__ b2,
                float* __restrict__ out)
{
    const int r = blockIdx.x * 256 + threadIdx.x;
    if (r >= 1024) return;
    float h[32];
    #pragma unroll
    for (int k = 0; k < 32; k++) h[k] = h3[r * 32 + k];
    float d1[8];
    #pragma unroll
    for (int j = 0; j < 8; j++) {
        float a = b1[j];
        #pragma unroll
        for (int k = 0; k < 32; k++) a += h[k] * w1[k * 8 + j];
        d1[j] = fmaxf(a, 0.0f);
    }
    #pragma unroll
    for (int c = 0; c < 3; c++) {
        float s = b2[c];
        #pragma unroll
        for (int j = 0; j < 8; j++) s += d1[j] * w2[j * 3 + c];
        out[r * 3 + c] = 1.0f / (1.0f + __expf(-s));
    }
}

extern "C" void kernel_launch(void* const* d_in, const int* in_sizes, int n_in,
                              void* d_out, int out_size, void* d_ws, size_t ws_size,
                              hipStream_t stream) {
    const float* x     = (const float*)d_in[0];
    const float* w1f_k = (const float*)d_in[1];
    const float* w1f_r = (const float*)d_in[2];
    const float* w1f_b = (const float*)d_in[3];
    const float* w1b_k = (const float*)d_in[4];
    const float* w1b_r = (const float*)d_in[5];
    const float* w1b_b = (const float*)d_in[6];
    const float* w2f_k = (const float*)d_in[7];
    const float* w2f_r = (const float*)d_in[8];
    const float* w2f_b = (const float*)d_in[9];
    const float* w2b_k = (const float*)d_in[10];
    const float* w2b_r = (const float*)d_in[11];
    const float* w2b_b = (const float*)d_in[12];
    const float* w3f_k = (const float*)d_in[13];
    const float* w3f_r = (const float*)d_in[14];
    const float* w3f_b = (const float*)d_in[15];
    const float* w3b_k = (const float*)d_in[16];
    const float* w3b_r = (const float*)d_in[17];
    const float* w3b_b = (const float*)d_in[18];
    const float* d3_w  = (const float*)d_in[19];
    const float* d3_b  = (const float*)d_in[20];
    const float* cls_w = (const float*)d_in[21];
    const float* cls_b = (const float*)d_in[22];

    char* ws = (char*)d_ws;
    // Arena A (reused 3x): xz1 134.2MB -> xz2 67.1MB -> xz3 33.6MB
    _Float16* xz = (_Float16*)ws;
    _Float16* h1 = (_Float16*)(ws + 134217728);                  // 32MB
    _Float16* h2 = (_Float16*)(ws + 134217728 + 33554432);       // 16.8MB
    float*    h3 = (float*)   (ws + 134217728 + 33554432 + 16777216);
    half8*    wf = (half8*)   (ws + 184680448);                  // 176KB packed frags
    float4*  bf4 = (float4*)  (ws + 184680448 + 180224);         // 14KB biases

    pack_wk<<<dim3(4), dim3(256), 0, stream>>>(
        w1f_k, w1f_b, w1b_k, w1b_b, w2f_k, w2f_b, w2b_k, w2b_b,
        w3f_k, w3f_b, w3b_k, w3b_b, wf, bf4);

    // L1: F=78 (3 k-tiles, fp32 in), U=64; LDS-staged, TPC=8 -> 2048 blocks
    xz_gemm<78, 96, 3, 64, true, 8, true><<<dim3(2048), dim3(256), 0, stream>>>(
        x, wf, bf4, xz);
    lstm_rec<64, 2, true><<<dim3(256), dim3(256), 0, stream>>>(
        xz, w1f_r, w1b_r, h1, nullptr);

    // L2: F=128, U=32; LDS-staged
    xz_gemm<128, 128, 4, 32, false, 8, true><<<dim3(2048), dim3(128), 0, stream>>>(
        h1, wf + 6144, bf4 + 512, xz);
    lstm_rec<32, 1, true><<<dim3(256), dim3(128), 0, stream>>>(
        xz, w2f_r, w2b_r, h2, nullptr);

    // L3: F=64, U=16; single wave -> direct loads
    xz_gemm<64, 64, 2, 16, false, 4, false><<<dim3(4096), dim3(64), 0, stream>>>(
        h2, wf + 10240, bf4 + 768, xz);
    lstm_rec<16, 1, false><<<dim3(256), dim3(64), 0, stream>>>(
        xz, w3f_r, w3b_r, nullptr, h3);

    dense_head<<<dim3(4), dim3(256), 0, stream>>>(h3, d3_w, d3_b, cls_w, cls_b, (float*)d_out);
}